// Round 10
// baseline (75.374 us; speedup 1.0000x reference)
//
#include <hip/hip_runtime.h>
#include <math.h>

#define NP 30
#define NX 13
#define ROWS 256
#define NBLK 2048   // 8 blocks/CU * 256 CUs: persistent grid-stride

typedef float v4f __attribute__((ext_vector_type(4)));
typedef float v2f __attribute__((ext_vector_type(2)));

__global__ __launch_bounds__(ROWS) void t1d_kernel(
    const float* __restrict__ x,
    const float* __restrict__ params,
    const float* __restrict__ CHO,
    const float* __restrict__ insulin_u,
    const float* __restrict__ last_Qsto,
    const float* __restrict__ last_foodtaken,
    float* __restrict__ out,
    int n)
{
    // R8's proven policy partition: x/scalars/out non-temporal (stream HBM,
    // no L3 alloc) so the 240 MB params array stays L3-resident.
    // New in R10: persistent blocks with register-double-buffered x staging —
    // next tile's nt loads issue BEFORE current tile's compute, hiding the
    // HBM stream latency under compute+store (T14 issue-early/write-late).
    __shared__ float lds_x[ROWS * NX];   // 13312 B: x rows, then outputs

    const int tid = threadIdx.x;
    const int ntiles = (n + ROWS - 1) / ROWS;
    int tile = blockIdx.x;
    if (tile >= ntiles) return;

    // ---- prologue: stage this block's first tile ----
    {
        const long long base = (long long)tile * ROWS;
        const int nrows0 = (int)(((long long)n - base) < ROWS ? ((long long)n - base) : ROWS);
        const float* srcx = x + base * NX;
        const v4f* s4 = (const v4f*)srcx;
        v4f* d4 = (v4f*)lds_x;
        if (nrows0 == ROWS) {   // 832 f4 = 3x256 + 64
            v4f a0 = __builtin_nontemporal_load(s4 + tid);
            v4f a1 = __builtin_nontemporal_load(s4 + tid + 256);
            v4f a2 = __builtin_nontemporal_load(s4 + tid + 512);
            d4[tid] = a0; d4[tid + 256] = a1; d4[tid + 512] = a2;
            if (tid < 64) d4[tid + 768] = __builtin_nontemporal_load(s4 + tid + 768);
        } else {
            const int totx = nrows0 * NX, nf4 = totx >> 2;
            for (int idx = tid; idx < nf4; idx += ROWS)
                d4[idx] = __builtin_nontemporal_load(s4 + idx);
            for (int g = (nf4 << 2) + tid; g < totx; g += ROWS)
                lds_x[g] = __builtin_nontemporal_load(srcx + g);
        }
    }
    __syncthreads();

    for (; tile < ntiles; tile += NBLK) {
        const long long base = (long long)tile * ROWS;
        const long long rem = (long long)n - base;
        const int nrows = (int)(rem < ROWS ? rem : ROWS);
        const int next = tile + NBLK;
        const bool havenext = next < ntiles;
        const bool nextfull = havenext && ((long long)next * ROWS + ROWS <= (long long)n);

        // ---- issue NEXT tile's x loads now (consume after the store) ----
        v4f a0, a1, a2, a3;
        if (nextfull) {
            const v4f* s4 = (const v4f*)(x + (long long)next * (ROWS * NX));
            a0 = __builtin_nontemporal_load(s4 + tid);
            a1 = __builtin_nontemporal_load(s4 + tid + 256);
            a2 = __builtin_nontemporal_load(s4 + tid + 512);
            if (tid < 64) a3 = __builtin_nontemporal_load(s4 + tid + 768);
        }

        // ---- compute current tile ----
        if (tid < nrows) {
            const long long i = base + tid;

            const v2f* pp = (const v2f*)(params + i * NP);  // cached, L3-resident
            v2f q0  = pp[0],  q1  = pp[1],  q2  = pp[2],  q3  = pp[3],  q4  = pp[4];
            v2f q5  = pp[5],  q6  = pp[6],  q7  = pp[7],  q8  = pp[8],  q9  = pp[9];
            v2f q10 = pp[10], q11 = pp[11], q12 = pp[12], q13 = pp[13], q14 = pp[14];

            float kmax = q0[0],  kmin = q0[1],  b    = q1[0],  d_   = q1[1];
            float kabs = q2[0],  f    = q2[1],  BW   = q3[0],  kp1  = q3[1];
            float kp2  = q4[0],  kp3  = q4[1],  Fsnc = q5[0],  ke1  = q5[1];
            float ke2  = q6[0],  k1   = q6[1],  k2   = q7[0],  Vm0  = q7[1];
            float Vmx  = q8[0],  Km0  = q8[1],  m1   = q9[0],  m2   = q9[1];
            float m4   = q10[0], m30  = q10[1], ka1  = q11[0], ka2  = q11[1];
            float kd   = q12[0], Vi   = q12[1], p2u  = q13[0], Ib   = q13[1];
            float ki   = q14[0], ksc  = q14[1];

            const float* xr = lds_x + tid * NX;  // own row, stride-13 conflict-free
            float x0 = xr[0], x1 = xr[1], x2 = xr[2], x3 = xr[3], x4 = xr[4];
            float x5 = xr[5], x6 = xr[6], x7 = xr[7], x8 = xr[8], x9 = xr[9];
            float x10 = xr[10], x11 = xr[11], x12 = xr[12];

            float cho = __builtin_nontemporal_load(CHO + i);
            float ins = __builtin_nontemporal_load(insulin_u + i);
            float lq  = __builtin_nontemporal_load(last_Qsto + i);
            float lf  = __builtin_nontemporal_load(last_foodtaken + i);

            float d       = cho * 1000.0f;
            float insulin = ins * 6000.0f / BW;

            float qsto = x0 + x1;
            float Dbar = lq + lf;
            bool has_food = Dbar > 0.0f;
            float Dbar_safe = has_food ? Dbar : 1.0f;
            float aa = 2.5f / (1.0f - b) / Dbar_safe;
            float cc = 2.5f / d_ / Dbar_safe;
            float kgut_eating = kmin + (kmax - kmin) * 0.5f *
                (tanhf(aa * (qsto - b * Dbar)) - tanhf(cc * (qsto - d_ * Dbar)) + 2.0f);
            float kgut = has_food ? kgut_eating : kmax;

            float o0 = -kmax * x0 + d;
            float o1 = kmax * x0 - x1 * kgut;
            float o2 = kgut * x1 - kabs * x2;

            float Rat  = f * kabs * x2 / BW;
            float EGPt = kp1 - kp2 * x3 - kp3 * x8;
            float Et   = (x3 > ke2) ? ke1 * (x3 - ke2) : 0.0f;
            float o3 = (fmaxf(EGPt, 0.0f) + Rat - Fsnc - Et - k1 * x3 + k2 * x4) *
                       (x3 >= 0.0f ? 1.0f : 0.0f);

            float Vmt  = Vm0 + Vmx * x6;
            float Uidt = Vmt * x4 / (Km0 + x4);
            float o4 = (-Uidt + k1 * x3 - k2 * x4) * (x4 >= 0.0f ? 1.0f : 0.0f);

            float o5 = (-(m2 + m4) * x5 + m1 * x9 + ka1 * x10 + ka2 * x11) *
                       (x5 >= 0.0f ? 1.0f : 0.0f);
            float It = x5 / Vi;
            float o6 = -p2u * x6 + p2u * (It - Ib);
            float o7 = -ki * (x7 - It);
            float o8 = -ki * (x8 - x7);
            float o9  = (-(m1 + m30) * x9 + m2 * x5) * (x9 >= 0.0f ? 1.0f : 0.0f);
            float o10 = (insulin - (ka1 + kd) * x10) * (x10 >= 0.0f ? 1.0f : 0.0f);
            float o11 = (kd * x10 - ka2 * x11) * (x11 >= 0.0f ? 1.0f : 0.0f);
            float o12 = (-ksc * x12 + ksc * x3) * (x12 >= 0.0f ? 1.0f : 0.0f);

            // own-row overwrite: no barrier needed (each thread reads/writes
            // only its own 13-float row)
            float* o = lds_x + tid * NX;
            o[0] = o0;  o[1] = o1;  o[2] = o2;  o[3] = o3;  o[4] = o4;
            o[5] = o5;  o[6] = o6;  o[7] = o7;  o[8] = o8;  o[9] = o9;
            o[10] = o10; o[11] = o11; o[12] = o12;
        }
        __syncthreads();

        // ---- coalesced nt float4 store of current tile's outputs ----
        {
            float* dst = out + base * NX;
            const v4f* s4 = (const v4f*)lds_x;
            v4f* d4 = (v4f*)dst;
            if (nrows == ROWS) {
                __builtin_nontemporal_store(s4[tid],       d4 + tid);
                __builtin_nontemporal_store(s4[tid + 256], d4 + tid + 256);
                __builtin_nontemporal_store(s4[tid + 512], d4 + tid + 512);
                if (tid < 64)
                    __builtin_nontemporal_store(s4[tid + 768], d4 + tid + 768);
            } else {
                const int tot = nrows * NX, nf4 = tot >> 2;
                for (int idx = tid; idx < nf4; idx += ROWS)
                    __builtin_nontemporal_store(s4[idx], d4 + idx);
                for (int g = (nf4 << 2) + tid; g < tot; g += ROWS)
                    dst[g] = lds_x[g];
            }
        }
        __syncthreads();

        // ---- write prefetched next-tile x into LDS ----
        if (havenext) {
            v4f* d4 = (v4f*)lds_x;
            if (nextfull) {
                d4[tid] = a0; d4[tid + 256] = a1; d4[tid + 512] = a2;
                if (tid < 64) d4[tid + 768] = a3;
            } else {
                const long long nb = (long long)next * ROWS;
                const int nr = (int)((long long)n - nb);   // 0 < nr < ROWS
                const int totx = nr * NX, nf4 = totx >> 2;
                const float* srcx = x + nb * NX;
                const v4f* s4 = (const v4f*)srcx;
                for (int idx = tid; idx < nf4; idx += ROWS)
                    d4[idx] = __builtin_nontemporal_load(s4 + idx);
                for (int g = (nf4 << 2) + tid; g < totx; g += ROWS)
                    lds_x[g] = __builtin_nontemporal_load(srcx + g);
            }
            __syncthreads();
        }
    }
}

extern "C" void kernel_launch(void* const* d_in, const int* in_sizes, int n_in,
                              void* d_out, int out_size, void* d_ws, size_t ws_size,
                              hipStream_t stream) {
    const float* x    = (const float*)d_in[0];
    const float* par  = (const float*)d_in[1];
    const float* CHO  = (const float*)d_in[2];
    const float* ins  = (const float*)d_in[3];
    const float* lq   = (const float*)d_in[4];
    const float* lf   = (const float*)d_in[5];
    float* out = (float*)d_out;
    int n = in_sizes[2];  // B (CHO length)

    int ntiles = (int)(((long long)n + ROWS - 1) / ROWS);
    int grid = ntiles < NBLK ? ntiles : NBLK;
    t1d_kernel<<<grid, ROWS, 0, stream>>>(x, par, CHO, ins, lq, lf, out, n);
}

// Round 11
// 74.575 us; speedup vs baseline: 1.0107x; 1.0107x over previous
//
#include <hip/hip_runtime.h>
#include <math.h>

#define NP 30
#define NX 13
#define ROWS 256

typedef float v4f __attribute__((ext_vector_type(4)));
typedef float v2f __attribute__((ext_vector_type(2)));

// ROOFLINE-CANDIDATE KERNEL (best: 73.08 µs, R9).
// Model: compulsory traffic across the L2<->(L3/HBM) boundary is 480 MB/pass
// (376 MB inputs + 104 MB outputs; nothing fits in 32 MB aggregate L2).
// 73.1 µs => 6.57 TB/s effective, above the 6.29 TB/s D2D-copy ceiling.
// Key mechanisms (each A/B-proven in R5-R9):
//  1. Policy partition: x + scalar streams + output use NON-TEMPORAL
//     loads/stores (sequential single-touch -> stream HBM, no L3 alloc),
//     so the 240 MB params array stays L3-resident (R8: 91.8 -> 73.2 µs).
//  2. Full-line coalesced nt float4 output stores via small LDS staging
//     (R5: avoids partial-line RMW, WRITE_SIZE exactly ideal 101.56 MB).
//  3. LDS kept at 13.3 KB (x buffer reused for outputs) -> 8 blocks/CU
//     (R6 showed 44 KB staging costs more occupancy than it buys).
//  4. params as 15 cached float2 loads (rows 8B-aligned at 120B stride).
__global__ __launch_bounds__(ROWS) void t1d_kernel(
    const float* __restrict__ x,
    const float* __restrict__ params,
    const float* __restrict__ CHO,
    const float* __restrict__ insulin_u,
    const float* __restrict__ last_Qsto,
    const float* __restrict__ last_foodtaken,
    float* __restrict__ out,
    int n)
{
    __shared__ float lds_x[ROWS * NX];   // 13312 B: x rows, then outputs

    const int tid = threadIdx.x;
    const long long blockStart = (long long)blockIdx.x * ROWS;
    const long long rem = (long long)n - blockStart;
    if (rem <= 0) return;
    const int nrows = rem < ROWS ? (int)rem : ROWS;

    // ---- stage x with coalesced NON-TEMPORAL float4 loads ----
    {
        const float* srcx = x + blockStart * NX;        // 13312B*blockIdx -> 16B aligned
        const int totx = nrows * NX;
        const int xf4 = totx >> 2;
        const v4f* sx4 = (const v4f*)srcx;
        v4f* dx4 = (v4f*)lds_x;
        for (int idx = tid; idx < xf4; idx += ROWS)
            dx4[idx] = __builtin_nontemporal_load(sx4 + idx);
        for (int g = (xf4 << 2) + tid; g < totx; g += ROWS)
            lds_x[g] = __builtin_nontemporal_load(srcx + g);
    }
    __syncthreads();

    if (tid < nrows) {
        const long long i = blockStart + tid;

        // params: NORMAL (cached) float2 loads — L3-resident working set
        const v2f* pp = (const v2f*)(params + i * NP);  // 8B-aligned (i*120B)
        v2f q0  = pp[0],  q1  = pp[1],  q2  = pp[2],  q3  = pp[3],  q4  = pp[4];
        v2f q5  = pp[5],  q6  = pp[6],  q7  = pp[7],  q8  = pp[8],  q9  = pp[9];
        v2f q10 = pp[10], q11 = pp[11], q12 = pp[12], q13 = pp[13], q14 = pp[14];

        float kmax = q0[0],  kmin = q0[1],  b    = q1[0],  d_   = q1[1];
        float kabs = q2[0],  f    = q2[1],  BW   = q3[0],  kp1  = q3[1];
        float kp2  = q4[0],  kp3  = q4[1],  Fsnc = q5[0],  ke1  = q5[1];
        float ke2  = q6[0],  k1   = q6[1],  k2   = q7[0],  Vm0  = q7[1];
        float Vmx  = q8[0],  Km0  = q8[1],  m1   = q9[0],  m2   = q9[1];
        float m4   = q10[0], m30  = q10[1], ka1  = q11[0], ka2  = q11[1];
        float kd   = q12[0], Vi   = q12[1], p2u  = q13[0], Ib   = q13[1];
        float ki   = q14[0], ksc  = q14[1];

        const float* xr = lds_x + tid * NX;  // stride-13: conflict-free
        float x0 = xr[0], x1 = xr[1], x2 = xr[2], x3 = xr[3], x4 = xr[4];
        float x5 = xr[5], x6 = xr[6], x7 = xr[7], x8 = xr[8], x9 = xr[9];
        float x10 = xr[10], x11 = xr[11], x12 = xr[12];

        // scalar streams: single-touch, stride-1 -> non-temporal
        float cho = __builtin_nontemporal_load(CHO + i);
        float ins = __builtin_nontemporal_load(insulin_u + i);
        float lq  = __builtin_nontemporal_load(last_Qsto + i);
        float lf  = __builtin_nontemporal_load(last_foodtaken + i);

        float d       = cho * 1000.0f;
        float insulin = ins * 6000.0f / BW;

        float qsto = x0 + x1;
        float Dbar = lq + lf;
        bool has_food = Dbar > 0.0f;
        float Dbar_safe = has_food ? Dbar : 1.0f;
        float aa = 2.5f / (1.0f - b) / Dbar_safe;
        float cc = 2.5f / d_ / Dbar_safe;
        float kgut_eating = kmin + (kmax - kmin) * 0.5f *
            (tanhf(aa * (qsto - b * Dbar)) - tanhf(cc * (qsto - d_ * Dbar)) + 2.0f);
        float kgut = has_food ? kgut_eating : kmax;

        float o0 = -kmax * x0 + d;
        float o1 = kmax * x0 - x1 * kgut;
        float o2 = kgut * x1 - kabs * x2;

        float Rat  = f * kabs * x2 / BW;
        float EGPt = kp1 - kp2 * x3 - kp3 * x8;
        float Et   = (x3 > ke2) ? ke1 * (x3 - ke2) : 0.0f;
        float o3 = (fmaxf(EGPt, 0.0f) + Rat - Fsnc - Et - k1 * x3 + k2 * x4) *
                   (x3 >= 0.0f ? 1.0f : 0.0f);

        float Vmt  = Vm0 + Vmx * x6;
        float Uidt = Vmt * x4 / (Km0 + x4);
        float o4 = (-Uidt + k1 * x3 - k2 * x4) * (x4 >= 0.0f ? 1.0f : 0.0f);

        float o5 = (-(m2 + m4) * x5 + m1 * x9 + ka1 * x10 + ka2 * x11) *
                   (x5 >= 0.0f ? 1.0f : 0.0f);
        float It = x5 / Vi;
        float o6 = -p2u * x6 + p2u * (It - Ib);
        float o7 = -ki * (x7 - It);
        float o8 = -ki * (x8 - x7);
        float o9  = (-(m1 + m30) * x9 + m2 * x5) * (x9 >= 0.0f ? 1.0f : 0.0f);
        float o10 = (insulin - (ka1 + kd) * x10) * (x10 >= 0.0f ? 1.0f : 0.0f);
        float o11 = (kd * x10 - ka2 * x11) * (x11 >= 0.0f ? 1.0f : 0.0f);
        float o12 = (-ksc * x12 + ksc * x3) * (x12 >= 0.0f ? 1.0f : 0.0f);

        // overwrite OWN row only -> no barrier needed before this
        float* o = lds_x + tid * NX;
        o[0] = o0;  o[1] = o1;  o[2] = o2;  o[3] = o3;  o[4] = o4;
        o[5] = o5;  o[6] = o6;  o[7] = o7;  o[8] = o8;  o[9] = o9;
        o[10] = o10; o[11] = o11; o[12] = o12;
    }
    __syncthreads();

    // ---- coalesced non-temporal float4 store of the contiguous chunk ----
    {
        float* dst = out + blockStart * NX;   // 16B aligned
        const int tot = nrows * NX;
        const int nf4 = tot >> 2;
        const v4f* s4 = (const v4f*)lds_x;
        v4f* d4 = (v4f*)dst;
        for (int idx = tid; idx < nf4; idx += ROWS)
            __builtin_nontemporal_store(s4[idx], d4 + idx);
        for (int g = (nf4 << 2) + tid; g < tot; g += ROWS)
            dst[g] = lds_x[g];
    }
}

extern "C" void kernel_launch(void* const* d_in, const int* in_sizes, int n_in,
                              void* d_out, int out_size, void* d_ws, size_t ws_size,
                              hipStream_t stream) {
    const float* x    = (const float*)d_in[0];
    const float* par  = (const float*)d_in[1];
    const float* CHO  = (const float*)d_in[2];
    const float* ins  = (const float*)d_in[3];
    const float* lq   = (const float*)d_in[4];
    const float* lf   = (const float*)d_in[5];
    float* out = (float*)d_out;
    int n = in_sizes[2];  // B (CHO length)

    int grid = (int)(((long long)n + ROWS - 1) / ROWS);
    t1d_kernel<<<grid, ROWS, 0, stream>>>(x, par, CHO, ins, lq, lf, out, n);
}